// Round 6
// baseline (265.678 us; speedup 1.0000x reference)
//
#include <hip/hip_runtime.h>

#define NHEADS 8
#define TQ 4
#define QH 16
#define QW 16
#define TK 4
#define KH 16
#define KW 16
#define DIM 64
#define BATCH 4
#define ROWS (BATCH * NHEADS * TQ * QH * QW)   // 32768

typedef float f4 __attribute__((ext_vector_type(4)));

// One WAVE per 2 consecutive q-rows (software-pipelined), 4 waves/block,
// 4096 blocks. No __syncthreads: each wave computes its rows' bias dots in
// lanes 0..35 into LDS and reads them back (same-wave DS ordering +
// wave_barrier). All 8 score float4s (both rows) are issued nontemporally
// before the dot chains; stores are nontemporal.
__global__ __launch_bounds__(256) void relpos_fused(
    const float* __restrict__ query,   // [ROWS,64]
    const float* __restrict__ scores,  // [ROWS,1024]
    const float* __restrict__ hemb,    // [31,64]
    const float* __restrict__ wemb,    // [31,64]
    const float* __restrict__ temb,    // [7,64]
    float* __restrict__ out)           // [ROWS,1024]
{
    const int lane = threadIdx.x & 63;
    const int wid  = threadIdx.x >> 6;              // wave 0..3
    const int row0 = ((blockIdx.x << 2) + wid) << 1; // 2 rows per wave
    const int pos  = row0 & 1023;
    const int t  = pos >> 8;
    const int h  = (pos >> 4) & 15;
    const int w0 = pos & 15;                         // row r has w = w0 + r (w0 even)

    // ---- Phase 0: issue both rows' score loads (8 f4/lane in flight, nt) ----
    const f4* sc0 = (const f4*)(scores + (size_t)row0 * 1024);
    const f4* sc1 = sc0 + 256;
    f4 a0 = __builtin_nontemporal_load(&sc0[lane]);
    f4 a1 = __builtin_nontemporal_load(&sc0[64 + lane]);
    f4 a2 = __builtin_nontemporal_load(&sc0[128 + lane]);
    f4 a3 = __builtin_nontemporal_load(&sc0[192 + lane]);
    f4 b0 = __builtin_nontemporal_load(&sc1[lane]);
    f4 b1 = __builtin_nontemporal_load(&sc1[64 + lane]);
    f4 b2 = __builtin_nontemporal_load(&sc1[128 + lane]);
    f4 b3 = __builtin_nontemporal_load(&sc1[192 + lane]);

    // ---- Phase 1: lanes 0..35 compute bias dots for both rows ----
    __shared__ float rel[4][2][40];  // [wave][row][0:16)=rel_h,[16:32)=rel_w,[32:36)=rel_t
    if (lane < 36) {
        const float* emb;
        int ebase;   // embedding row index for r=0
        if (lane < 16)      { emb = hemb; ebase = h - lane + 15; }
        else if (lane < 32) { emb = wemb; ebase = w0 - (lane - 16) + 15; }
        else                { emb = temb; ebase = t - (lane - 32) + 3; }
        const int isw = (lane >= 16 && lane < 32);   // w-index shifts with r
#pragma unroll
        for (int r = 0; r < 2; ++r) {
            const f4* e4 = (const f4*)(emb + (size_t)(ebase + (isw ? r : 0)) * DIM);
            const f4* q4 = (const f4*)(query + (size_t)(row0 + r) * DIM);
            float d0 = 0.f, d1 = 0.f, d2 = 0.f, d3 = 0.f;
#pragma unroll
            for (int c = 0; c < DIM / 4; c += 4) {
                f4 qa = q4[c + 0], ea = e4[c + 0];
                f4 qb = q4[c + 1], eb = e4[c + 1];
                f4 qc = q4[c + 2], ec = e4[c + 2];
                f4 qd = q4[c + 3], ed = e4[c + 3];
                d0 += qa.x * ea.x + qa.y * ea.y + qa.z * ea.z + qa.w * ea.w;
                d1 += qb.x * eb.x + qb.y * eb.y + qb.z * eb.z + qb.w * eb.w;
                d2 += qc.x * ec.x + qc.y * ec.y + qc.z * ec.z + qc.w * ec.w;
                d3 += qd.x * ed.x + qd.y * ed.y + qd.z * ed.z + qd.w * ed.w;
            }
            rel[wid][r][lane] = (d0 + d1) + (d2 + d3);
        }
    }
    __builtin_amdgcn_wave_barrier();   // pin DS write-before-read ordering (free)

    // ---- Phase 2: combine + nt store. Lane's float4 j = 64*tk + lane. ----
    const int kh  = lane >> 2;
    const int kw0 = (lane & 3) << 2;

#pragma unroll
    for (int r = 0; r < 2; ++r) {
        const float* rl = rel[wid][r];
        const float bh = rl[kh];
        const f4 bw = *(const f4*)&rl[16 + kw0];
        const f4 bt = *(const f4*)&rl[32];           // rel_t[0..3]
        f4* o4 = (f4*)(out + (size_t)(row0 + r) * 1024);
        const f4 s0 = r ? b0 : a0, s1 = r ? b1 : a1;
        const f4 s2 = r ? b2 : a2, s3 = r ? b3 : a3;
        f4 o;
        o = s0 + (bh + bt.x); o += bw;
        __builtin_nontemporal_store(o, &o4[lane]);
        o = s1 + (bh + bt.y); o += bw;
        __builtin_nontemporal_store(o, &o4[64 + lane]);
        o = s2 + (bh + bt.z); o += bw;
        __builtin_nontemporal_store(o, &o4[128 + lane]);
        o = s3 + (bh + bt.w); o += bw;
        __builtin_nontemporal_store(o, &o4[192 + lane]);
    }
}

extern "C" void kernel_launch(void* const* d_in, const int* in_sizes, int n_in,
                              void* d_out, int out_size, void* d_ws, size_t ws_size,
                              hipStream_t stream) {
    const float* query  = (const float*)d_in[0];
    const float* scores = (const float*)d_in[1];
    const float* hemb   = (const float*)d_in[2];
    const float* wemb   = (const float*)d_in[3];
    const float* temb   = (const float*)d_in[4];
    float* out = (float*)d_out;

    relpos_fused<<<dim3(ROWS / 8), dim3(256), 0, stream>>>(
        query, scores, hemb, wemb, temb, out);
}